// Round 7
// baseline (126.095 us; speedup 1.0000x reference)
//
#include <hip/hip_runtime.h>
#include <hip/hip_bf16.h>

#define NN 100000
#define EE 1600000
#define ET (EE + NN)            // edges incl. self loops
#define HID 64
#define NEG 0.2f
#define NBUK 782                // ceil(NN/128) buckets of 128 dst nodes
#define SCT_TILE 2048           // edges per block in scatter phase
#define BUKCAP 4096             // padded per-bucket capacity (mean 2176, sigma~47)
#define SH_CAP 4096

typedef unsigned short ushort_t;
#define BF(u)   __uint_as_float((unsigned)(u) << 16)
#define BFLO(u) __uint_as_float((unsigned)(u) << 16)
#define BFHI(u) __uint_as_float((unsigned)(u) & 0xFFFF0000u)

// ---------------- kernel 0: h1 = x@W1 (bf16), ss1/sd1 scores; also zeroes bcur ----------------
__global__ __launch_bounds__(256) void k_proj(const float* __restrict__ x,
                                              const float* __restrict__ W1,
                                              const float* __restrict__ a_src1,
                                              const float* __restrict__ a_dst1,
                                              ushort_t* __restrict__ h1b,
                                              float* __restrict__ ss1,
                                              float* __restrict__ sd1,
                                              int* __restrict__ bcur) {
    if (blockIdx.x == 0) {
        for (int i = threadIdx.x; i < 1024; i += 256) bcur[i] = 0;
    }
    int wid  = threadIdx.x >> 6;
    int lane = threadIdx.x & 63;
    int n = blockIdx.x * 4 + wid;
    if (n >= NN) return;
    float h = 0.f;
#pragma unroll
    for (int k = 0; k < 5; ++k) h += x[n * 5 + k] * W1[k * HID + lane];
    unsigned u = __float_as_uint(h);
    unsigned r = (u + 0x7FFFu + ((u >> 16) & 1u)) >> 16;   // RNE bf16
    h1b[(size_t)n * HID + lane] = (ushort_t)r;
    float hq = BF(r);                 // scores from QUANTIZED h for consistency
    float a = hq * a_src1[lane];
    float b = hq * a_dst1[lane];
#pragma unroll
    for (int o = 32; o; o >>= 1) { a += __shfl_xor(a, o); b += __shfl_xor(b, o); }
    if (lane == 0) { ss1[n] = a; sd1[n] = b; }
}

// ---------------- CSR build ----------------
__global__ __launch_bounds__(256) void k_bscatter(const int* __restrict__ ei,
                                                  int* __restrict__ bcur,
                                                  unsigned* __restrict__ pairs) {
    __shared__ unsigned sp[SCT_TILE];
    __shared__ unsigned ga[SCT_TILE];
    __shared__ int h[NBUK], loc[NBUK], cur[NBUK];
    __shared__ int wsum[4];
    int tid = threadIdx.x;
    int wid = tid >> 6, lane = tid & 63;
    int base = blockIdx.x * SCT_TILE;
    int tilecnt = ET - base; if (tilecnt > SCT_TILE) tilecnt = SCT_TILE;

    for (int i = tid; i < NBUK; i += 256) h[i] = 0;
    __syncthreads();
    int sreg[SCT_TILE / 256], dreg[SCT_TILE / 256];
#pragma unroll
    for (int it = 0; it < SCT_TILE / 256; ++it) {
        int i = base + it * 256 + tid;
        if (i < ET) {
            int s, d;
            if (i < EE) { s = ei[i]; d = ei[EE + i]; }
            else        { s = i - EE; d = s; }
            sreg[it] = s; dreg[it] = d;
            atomicAdd(&h[d >> 7], 1);
        } else dreg[it] = -1;
    }
    __syncthreads();
    int b0 = tid * 4;
    int s0 = 0;
    if (b0 < NBUK)
        for (int k = 0; k < 4 && b0 + k < NBUK; ++k) s0 += h[b0 + k];
    int incl = s0;
#pragma unroll
    for (int o = 1; o < 64; o <<= 1) {
        int t = __shfl(incl, (lane - o) & 63);
        if (lane >= o) incl += t;
    }
    if (lane == 63) wsum[wid] = incl;
    __syncthreads();
    int wpref = 0;
    for (int w = 0; w < wid; ++w) wpref += wsum[w];
    if (b0 < NBUK) {
        int run = wpref + incl - s0;
        for (int k = 0; k < 4 && b0 + k < NBUK; ++k) {
            loc[b0 + k] = run;
            run += h[b0 + k];
        }
    }
    __syncthreads();
    for (int i = tid; i < NBUK; i += 256) {
        int c = h[i];
        cur[i] = c ? (atomicAdd(&bcur[i], c) + i * BUKCAP - loc[i]) : 0;
    }
    __syncthreads();
#pragma unroll
    for (int it = 0; it < SCT_TILE / 256; ++it) {
        if (dreg[it] >= 0) {
            int s = sreg[it], d = dreg[it];
            int b = d >> 7;
            unsigned pk = ((unsigned)(d & 127) << 17) | (unsigned)s;
            int pos = atomicAdd(&loc[b], 1);
            sp[pos] = pk;
            ga[pos] = (unsigned)(cur[b] + pos);
        }
    }
    __syncthreads();
    for (int i = tid; i < tilecnt; i += 256)
        pairs[ga[i]] = sp[i];
}

__global__ __launch_bounds__(256) void k_bsort(const int* __restrict__ bcur,
                                               unsigned* __restrict__ pairs,
                                               int* __restrict__ rowptr,
                                               int* __restrict__ cntd) {
    __shared__ unsigned sp[SH_CAP];
    __shared__ int hist[128], sc[128], cur2[128];
    int b = blockIdx.x;
    int cnt = bcur[b];
    if (cnt > SH_CAP) cnt = SH_CAP;
    int base = b * BUKCAP;
    int tid = threadIdx.x;
    if (tid < 128) hist[tid] = 0;
    __syncthreads();
    for (int i = tid; i < cnt; i += 256) {
        unsigned p = pairs[base + i];
        sp[i] = p;
        atomicAdd(&hist[p >> 17], 1);
    }
    __syncthreads();
    if (tid < 64) {
        int v0 = hist[2 * tid], v1 = hist[2 * tid + 1];
        int s = v0 + v1;
#pragma unroll
        for (int o = 1; o < 64; o <<= 1) {
            int t = __shfl(s, (tid - o) & 63);
            if (tid >= o) s += t;
        }
        int excl = s - v0 - v1;
        sc[2 * tid] = excl;
        sc[2 * tid + 1] = excl + v0;
    }
    __syncthreads();
    int nbase = b << 7;
    if (tid < 128 && nbase + tid < NN) {
        rowptr[nbase + tid] = base + sc[tid];
        cntd[nbase + tid]   = hist[tid];
        cur2[tid] = sc[tid];
    }
    __syncthreads();
    int* adj = (int*)pairs;
    for (int i = tid; i < cnt; i += 256) {
        unsigned p = sp[i];
        int ld = p >> 17;
        int pos = atomicAdd(&cur2[ld], 1);
        adj[base + pos] = (int)(p & 0x1FFFF);
    }
}

// ---------------- layer 1: full-wave single-node fallback (deg>32) ----------------
__device__ __forceinline__ void agg1_node(int n, int lane, int wid,
                                          float (*lw)[64], int (*lsrc)[64],
                                          const int* __restrict__ rowptr,
                                          const int* __restrict__ cntd,
                                          const int* __restrict__ adj,
                                          const float* __restrict__ ss1,
                                          const float* __restrict__ sd1,
                                          const ushort_t* __restrict__ h1b,
                                          const float* __restrict__ b1,
                                          const float* __restrict__ W2,
                                          float* __restrict__ h2) {
    int off = rowptr[n], deg = cntd[n];
    float sdn = sd1[n];
    if (deg <= 64) {
        int s = 0; float e = -1e30f;
        if (lane < deg) {
            s = adj[off + lane];
            float t = ss1[s] + sdn;
            e = t > 0.f ? t : NEG * t;
        }
        float m = e;
#pragma unroll
        for (int o = 32; o; o >>= 1) m = fmaxf(m, __shfl_xor(m, o));
        float p = (lane < deg) ? __expf(e - m) : 0.f;
        float ds = p;
#pragma unroll
        for (int o = 32; o; o >>= 1) ds += __shfl_xor(ds, o);
        float w = p * (1.0f / ds);
        lw[wid][lane] = w;
        lsrc[wid][lane] = s;
        int g = lane >> 3, c = lane & 7;
        float a0[8] = {0,0,0,0,0,0,0,0};
        for (int tb = 0; tb < deg; tb += 8) {
            int t = tb + g;
            if (t < deg) {
                float w0 = lw[wid][t];
                const uint4 v = *(const uint4*)(h1b + (size_t)lsrc[wid][t] * HID + (c << 3));
                a0[0] += w0 * BFLO(v.x); a0[1] += w0 * BFHI(v.x);
                a0[2] += w0 * BFLO(v.y); a0[3] += w0 * BFHI(v.y);
                a0[4] += w0 * BFLO(v.z); a0[5] += w0 * BFHI(v.z);
                a0[6] += w0 * BFLO(v.w); a0[7] += w0 * BFHI(v.w);
            }
        }
#pragma unroll
        for (int o = 8; o <= 32; o <<= 1) {
#pragma unroll
            for (int k = 0; k < 8; ++k) a0[k] += __shfl_xor(a0[k], o);
        }
        const float4 bA = *(const float4*)(b1 + (c << 3));
        const float4 bB = *(const float4*)(b1 + (c << 3) + 4);
        const float4 WA = *(const float4*)(W2 + (c << 3));
        const float4 WB = *(const float4*)(W2 + (c << 3) + 4);
        float p2 = fmaxf(a0[0] + bA.x, 0.f) * WA.x + fmaxf(a0[1] + bA.y, 0.f) * WA.y
                 + fmaxf(a0[2] + bA.z, 0.f) * WA.z + fmaxf(a0[3] + bA.w, 0.f) * WA.w
                 + fmaxf(a0[4] + bB.x, 0.f) * WB.x + fmaxf(a0[5] + bB.y, 0.f) * WB.y
                 + fmaxf(a0[6] + bB.z, 0.f) * WB.z + fmaxf(a0[7] + bB.w, 0.f) * WB.w;
#pragma unroll
        for (int o = 1; o <= 4; o <<= 1) p2 += __shfl_xor(p2, o);
        if (lane == 0) h2[n] = p2;
    } else {
        float acc = 0.f;
        float m = -1e30f;
        for (int j0 = 0; j0 < deg; j0 += 64) {
            int j = j0 + lane;
            if (j < deg) {
                int s = adj[off + j];
                float e = ss1[s] + sdn;
                e = e > 0.f ? e : NEG * e;
                m = fmaxf(m, e);
            }
        }
#pragma unroll
        for (int o = 32; o; o >>= 1) m = fmaxf(m, __shfl_xor(m, o));
        float dsum = 0.f;
        for (int j0 = 0; j0 < deg; j0 += 64) {
            int j = j0 + lane;
            if (j < deg) {
                int s = adj[off + j];
                float e = ss1[s] + sdn;
                e = e > 0.f ? e : NEG * e;
                dsum += __expf(e - m);
            }
        }
#pragma unroll
        for (int o = 32; o; o >>= 1) dsum += __shfl_xor(dsum, o);
        float inv = 1.0f / dsum;
        for (int j0 = 0; j0 < deg; j0 += 64) {
            int j = j0 + lane;
            float w = 0.f; int s = 0;
            if (j < deg) {
                s = adj[off + j];
                float e = ss1[s] + sdn;
                e = e > 0.f ? e : NEG * e;
                w = __expf(e - m) * inv;
            }
            int lim = deg - j0; if (lim > 64) lim = 64;
            for (int t = 0; t < lim; ++t) {
                float cc = __shfl(w, t);
                int  sj = __shfl(s, t);
                acc += cc * BF(h1b[(size_t)sj * HID + lane]);
            }
        }
        float v = fmaxf(acc + b1[lane], 0.f);
        float p2 = v * W2[lane];
#pragma unroll
        for (int o = 32; o; o >>= 1) p2 += __shfl_xor(p2, o);
        if (lane == 0) h2[n] = p2;
    }
}

// ---------------- layer 1: 4 nodes per wave (two interleaved 32-lane pairs) ----------------
__global__ __launch_bounds__(256) void k_agg1(const int* __restrict__ rowptr,
                                              const int* __restrict__ cntd,
                                              const int* __restrict__ adj,
                                              const float* __restrict__ ss1,
                                              const float* __restrict__ sd1,
                                              const ushort_t* __restrict__ h1b,
                                              const float* __restrict__ b1,
                                              const float* __restrict__ W2,
                                              float* __restrict__ h2) {
    __shared__ float lwA[4][64], lwB[4][64];
    __shared__ int   lsA[4][64], lsB[4][64];
    int wid  = threadIdx.x >> 6;
    int lane = threadIdx.x & 63;
    int n0 = (blockIdx.x * 4 + wid) * 4;
    if (n0 >= NN) return;
    int d0 = cntd[n0], d1 = cntd[n0 + 1], d2 = cntd[n0 + 2], d3 = cntd[n0 + 3];

    if (d0 <= 32 && d1 <= 32 && d2 <= 32 && d3 <= 32) {
        int half = lane >> 5, li = lane & 31;
        int nA = n0 + half, nB = n0 + 2 + half;
        int offA = rowptr[nA], offB = rowptr[nB];
        int degA = half ? d1 : d0, degB = half ? d3 : d2;
        float sdA = sd1[nA], sdB = sd1[nB];
        int sA = 0, sB = 0; float eA = -1e30f, eB = -1e30f;
        if (li < degA) {
            sA = adj[offA + li];
            float t = ss1[sA] + sdA;
            eA = t > 0.f ? t : NEG * t;
        }
        if (li < degB) {
            sB = adj[offB + li];
            float t = ss1[sB] + sdB;
            eB = t > 0.f ? t : NEG * t;
        }
        float mA = eA, mB = eB;
#pragma unroll
        for (int o = 1; o <= 16; o <<= 1) {
            mA = fmaxf(mA, __shfl_xor(mA, o));
            mB = fmaxf(mB, __shfl_xor(mB, o));
        }
        float pA = (li < degA) ? __expf(eA - mA) : 0.f;
        float pB = (li < degB) ? __expf(eB - mB) : 0.f;
        float dsA = pA, dsB = pB;
#pragma unroll
        for (int o = 1; o <= 16; o <<= 1) {
            dsA += __shfl_xor(dsA, o);
            dsB += __shfl_xor(dsB, o);
        }
        lwA[wid][lane] = pA * (1.0f / dsA); lsA[wid][lane] = sA;
        lwB[wid][lane] = pB * (1.0f / dsB); lsB[wid][lane] = sB;
        // gather: per half 4 subgroups x 8 lanes; A and B rows issued together
        int g = (lane >> 3) & 3, c = lane & 7;
        int lbase = half << 5;
        float aA[8] = {0,0,0,0,0,0,0,0};
        float aB[8] = {0,0,0,0,0,0,0,0};
        int mdA = d0 > d1 ? d0 : d1;
        int mdB = d2 > d3 ? d2 : d3;
        int md = mdA > mdB ? mdA : mdB;
        for (int tb = 0; tb < md; tb += 4) {
            int t = tb + g;
            if (t < degA) {
                float w0 = lwA[wid][lbase + t];
                const uint4 v = *(const uint4*)(h1b + (size_t)lsA[wid][lbase + t] * HID + (c << 3));
                aA[0] += w0 * BFLO(v.x); aA[1] += w0 * BFHI(v.x);
                aA[2] += w0 * BFLO(v.y); aA[3] += w0 * BFHI(v.y);
                aA[4] += w0 * BFLO(v.z); aA[5] += w0 * BFHI(v.z);
                aA[6] += w0 * BFLO(v.w); aA[7] += w0 * BFHI(v.w);
            }
            if (t < degB) {
                float w1 = lwB[wid][lbase + t];
                const uint4 v = *(const uint4*)(h1b + (size_t)lsB[wid][lbase + t] * HID + (c << 3));
                aB[0] += w1 * BFLO(v.x); aB[1] += w1 * BFHI(v.x);
                aB[2] += w1 * BFLO(v.y); aB[3] += w1 * BFHI(v.y);
                aB[4] += w1 * BFLO(v.z); aB[5] += w1 * BFHI(v.z);
                aB[6] += w1 * BFLO(v.w); aB[7] += w1 * BFHI(v.w);
            }
        }
        // reduce over the 4 subgroups within each half
#pragma unroll
        for (int o = 8; o <= 16; o <<= 1) {
#pragma unroll
            for (int k = 0; k < 8; ++k) {
                aA[k] += __shfl_xor(aA[k], o);
                aB[k] += __shfl_xor(aB[k], o);
            }
        }
        const float4 b4l = *(const float4*)(b1 + (c << 3));
        const float4 b4h = *(const float4*)(b1 + (c << 3) + 4);
        const float4 W4l = *(const float4*)(W2 + (c << 3));
        const float4 W4h = *(const float4*)(W2 + (c << 3) + 4);
        float p2A = fmaxf(aA[0] + b4l.x, 0.f) * W4l.x + fmaxf(aA[1] + b4l.y, 0.f) * W4l.y
                  + fmaxf(aA[2] + b4l.z, 0.f) * W4l.z + fmaxf(aA[3] + b4l.w, 0.f) * W4l.w
                  + fmaxf(aA[4] + b4h.x, 0.f) * W4h.x + fmaxf(aA[5] + b4h.y, 0.f) * W4h.y
                  + fmaxf(aA[6] + b4h.z, 0.f) * W4h.z + fmaxf(aA[7] + b4h.w, 0.f) * W4h.w;
        float p2B = fmaxf(aB[0] + b4l.x, 0.f) * W4l.x + fmaxf(aB[1] + b4l.y, 0.f) * W4l.y
                  + fmaxf(aB[2] + b4l.z, 0.f) * W4l.z + fmaxf(aB[3] + b4l.w, 0.f) * W4l.w
                  + fmaxf(aB[4] + b4h.x, 0.f) * W4h.x + fmaxf(aB[5] + b4h.y, 0.f) * W4h.y
                  + fmaxf(aB[6] + b4h.z, 0.f) * W4h.z + fmaxf(aB[7] + b4h.w, 0.f) * W4h.w;
#pragma unroll
        for (int o = 1; o <= 4; o <<= 1) {
            p2A += __shfl_xor(p2A, o);
            p2B += __shfl_xor(p2B, o);
        }
        if (li == 0) { h2[nA] = p2A; h2[nB] = p2B; }
    } else {
        agg1_node(n0,     lane, wid, lwA, lsA, rowptr, cntd, adj, ss1, sd1, h1b, b1, W2, h2);
        agg1_node(n0 + 1, lane, wid, lwA, lsA, rowptr, cntd, adj, ss1, sd1, h1b, b1, W2, h2);
        agg1_node(n0 + 2, lane, wid, lwA, lsA, rowptr, cntd, adj, ss1, sd1, h1b, b1, W2, h2);
        agg1_node(n0 + 3, lane, wid, lwA, lsA, rowptr, cntd, adj, ss1, sd1, h1b, b1, W2, h2);
    }
}

// ---------------- layer 2: full-wave single-node fallback ----------------
__device__ __forceinline__ void agg2_node(int n, int lane,
                                          const int* __restrict__ rowptr,
                                          const int* __restrict__ cntd,
                                          const int* __restrict__ adj,
                                          const float* __restrict__ h2,
                                          float as2v, float ad2v, float b2v,
                                          float* __restrict__ out) {
    int off = rowptr[n], deg = cntd[n];
    float sdn = h2[n] * ad2v;
    float m = -1e30f;
    for (int j0 = 0; j0 < deg; j0 += 64) {
        int j = j0 + lane;
        if (j < deg) {
            int s = adj[off + j];
            float e = h2[s] * as2v + sdn;
            e = e > 0.f ? e : NEG * e;
            m = fmaxf(m, e);
        }
    }
#pragma unroll
    for (int o = 32; o; o >>= 1) m = fmaxf(m, __shfl_xor(m, o));
    float dsum = 0.f, nsum = 0.f;
    for (int j0 = 0; j0 < deg; j0 += 64) {
        int j = j0 + lane;
        if (j < deg) {
            int s = adj[off + j];
            float hv = h2[s];
            float e = hv * as2v + sdn;
            e = e > 0.f ? e : NEG * e;
            float ex = __expf(e - m);
            dsum += ex;
            nsum += ex * hv;
        }
    }
#pragma unroll
    for (int o = 32; o; o >>= 1) { dsum += __shfl_xor(dsum, o); nsum += __shfl_xor(nsum, o); }
    if (lane == 0) out[n] = nsum / dsum + b2v;
}

// ---------------- layer 2: 4 nodes per wave ----------------
__global__ __launch_bounds__(256) void k_agg2(const int* __restrict__ rowptr,
                                              const int* __restrict__ cntd,
                                              const int* __restrict__ adj,
                                              const float* __restrict__ h2,
                                              const float* __restrict__ as2,
                                              const float* __restrict__ ad2,
                                              const float* __restrict__ b2,
                                              float* __restrict__ out) {
    int wid  = threadIdx.x >> 6;
    int lane = threadIdx.x & 63;
    int n0 = (blockIdx.x * 4 + wid) * 4;
    if (n0 >= NN) return;
    float as2v = as2[0], ad2v = ad2[0], b2v = b2[0];
    int d0 = cntd[n0], d1 = cntd[n0 + 1], d2 = cntd[n0 + 2], d3 = cntd[n0 + 3];

    if (d0 <= 32 && d1 <= 32 && d2 <= 32 && d3 <= 32) {
        int half = lane >> 5, li = lane & 31;
        int nA = n0 + half, nB = n0 + 2 + half;
        int offA = rowptr[nA], offB = rowptr[nB];
        int degA = half ? d1 : d0, degB = half ? d3 : d2;
        float sdA = h2[nA] * ad2v, sdB = h2[nB] * ad2v;
        float hvA = 0.f, hvB = 0.f, eA = -1e30f, eB = -1e30f;
        if (li < degA) {
            hvA = h2[adj[offA + li]];
            float t = hvA * as2v + sdA;
            eA = t > 0.f ? t : NEG * t;
        }
        if (li < degB) {
            hvB = h2[adj[offB + li]];
            float t = hvB * as2v + sdB;
            eB = t > 0.f ? t : NEG * t;
        }
        float mA = eA, mB = eB;
#pragma unroll
        for (int o = 1; o <= 16; o <<= 1) {
            mA = fmaxf(mA, __shfl_xor(mA, o));
            mB = fmaxf(mB, __shfl_xor(mB, o));
        }
        float pA = (li < degA) ? __expf(eA - mA) : 0.f;
        float pB = (li < degB) ? __expf(eB - mB) : 0.f;
        float dsA = pA, dsB = pB, nsA = pA * hvA, nsB = pB * hvB;
#pragma unroll
        for (int o = 1; o <= 16; o <<= 1) {
            dsA += __shfl_xor(dsA, o); nsA += __shfl_xor(nsA, o);
            dsB += __shfl_xor(dsB, o); nsB += __shfl_xor(nsB, o);
        }
        if (li == 0) {
            out[nA] = nsA / dsA + b2v;
            out[nB] = nsB / dsB + b2v;
        }
    } else {
        agg2_node(n0,     lane, rowptr, cntd, adj, h2, as2v, ad2v, b2v, out);
        agg2_node(n0 + 1, lane, rowptr, cntd, adj, h2, as2v, ad2v, b2v, out);
        agg2_node(n0 + 2, lane, rowptr, cntd, adj, h2, as2v, ad2v, b2v, out);
        agg2_node(n0 + 3, lane, rowptr, cntd, adj, h2, as2v, ad2v, b2v, out);
    }
}

extern "C" void kernel_launch(void* const* d_in, const int* in_sizes, int n_in,
                              void* d_out, int out_size, void* d_ws, size_t ws_size,
                              hipStream_t stream) {
    const float* x      = (const float*)d_in[0];
    const int*   ei     = (const int*)d_in[1];
    const float* W1     = (const float*)d_in[2];
    const float* a_src1 = (const float*)d_in[3];
    const float* a_dst1 = (const float*)d_in[4];
    const float* b1     = (const float*)d_in[5];
    const float* W2     = (const float*)d_in[6];
    const float* as2    = (const float*)d_in[7];
    const float* ad2    = (const float*)d_in[8];
    const float* b2     = (const float*)d_in[9];
    float* out = (float*)d_out;

    // workspace layout
    ushort_t* h1b = (ushort_t*)d_ws;                    // N*64 bf16 = 12.8MB
    float* ss1  = (float*)(h1b + (size_t)NN * HID);     // N
    float* sd1  = ss1 + NN;                             // N
    float* h2   = sd1 + NN;                             // N
    int* rowptr = (int*)(h2 + NN);                      // N
    int* cntd   = rowptr + NN;                          // N
    int* bcur   = cntd + NN;                            // 1024
    unsigned* pairs = (unsigned*)(bcur + 1024);         // NBUK*BUKCAP (reused as adj)
    int* adj    = (int*)pairs;

    const int NSCT = (ET + SCT_TILE - 1) / SCT_TILE;    // 831
    const int NQUAD = (NN + 15) / 16;                   // 6250 blocks, 4 nodes/wave

    k_proj<<<(NN + 3) / 4, 256, 0, stream>>>(x, W1, a_src1, a_dst1, h1b, ss1, sd1, bcur);
    k_bscatter<<<NSCT, 256, 0, stream>>>(ei, bcur, pairs);
    k_bsort<<<NBUK, 256, 0, stream>>>(bcur, pairs, rowptr, cntd);
    k_agg1<<<NQUAD, 256, 0, stream>>>(rowptr, cntd, adj, ss1, sd1, h1b, b1, W2, h2);
    k_agg2<<<NQUAD, 256, 0, stream>>>(rowptr, cntd, adj, h2, as2, ad2, b2, out);
}

// Round 8
// 105.574 us; speedup vs baseline: 1.1944x; 1.1944x over previous
//
#include <hip/hip_runtime.h>
#include <hip/hip_bf16.h>

#define NN 100000
#define EE 1600000
#define ET (EE + NN)            // edges incl. self loops
#define HID 64
#define NEG 0.2f
#define NBUK 782                // ceil(NN/128) buckets of 128 dst nodes
#define SCT_TILE 4096           // edges per block in scatter phase
#define BUKCAP 4096             // padded per-bucket capacity (mean 2176, sigma~47)
#define SH_CAP 4096

// ---------------- kernel 0: xp = pad(x) [N][8] f32; ss1/sd1 node scores; zero bcur ----------------
__global__ __launch_bounds__(256) void k_proj(const float* __restrict__ x,
                                              const float* __restrict__ W1,
                                              const float* __restrict__ a_src1,
                                              const float* __restrict__ a_dst1,
                                              float* __restrict__ xp,
                                              float* __restrict__ ss1,
                                              float* __restrict__ sd1,
                                              int* __restrict__ bcur) {
    if (blockIdx.x == 0) {
        for (int i = threadIdx.x; i < 1024; i += 256) bcur[i] = 0;
    }
    int wid  = threadIdx.x >> 6;
    int lane = threadIdx.x & 63;
    int n = blockIdx.x * 4 + wid;
    if (n >= NN) return;
    float h = 0.f;
#pragma unroll
    for (int k = 0; k < 5; ++k) h += x[n * 5 + k] * W1[k * HID + lane];
    float a = h * a_src1[lane];
    float b = h * a_dst1[lane];
#pragma unroll
    for (int o = 32; o; o >>= 1) { a += __shfl_xor(a, o); b += __shfl_xor(b, o); }
    if (lane == 0) { ss1[n] = a; sd1[n] = b; }
    if (lane < 8) xp[(size_t)n * 8 + lane] = (lane < 5) ? x[n * 5 + lane] : 0.f;
}

// ---------------- CSR build ----------------
__global__ __launch_bounds__(256) void k_bscatter(const int* __restrict__ ei,
                                                  int* __restrict__ bcur,
                                                  unsigned* __restrict__ pairs) {
    __shared__ unsigned sp[SCT_TILE];
    __shared__ unsigned ga[SCT_TILE];
    __shared__ int h[NBUK], loc[NBUK], cur[NBUK];
    __shared__ int wsum[4];
    int tid = threadIdx.x;
    int wid = tid >> 6, lane = tid & 63;
    int base = blockIdx.x * SCT_TILE;
    int tilecnt = ET - base; if (tilecnt > SCT_TILE) tilecnt = SCT_TILE;

    for (int i = tid; i < NBUK; i += 256) h[i] = 0;
    __syncthreads();
    int sreg[SCT_TILE / 256], dreg[SCT_TILE / 256];
#pragma unroll
    for (int it = 0; it < SCT_TILE / 256; ++it) {
        int i = base + it * 256 + tid;
        if (i < ET) {
            int s, d;
            if (i < EE) { s = ei[i]; d = ei[EE + i]; }
            else        { s = i - EE; d = s; }
            sreg[it] = s; dreg[it] = d;
            atomicAdd(&h[d >> 7], 1);
        } else dreg[it] = -1;
    }
    __syncthreads();
    int b0 = tid * 4;
    int s0 = 0;
    if (b0 < NBUK)
        for (int k = 0; k < 4 && b0 + k < NBUK; ++k) s0 += h[b0 + k];
    int incl = s0;
#pragma unroll
    for (int o = 1; o < 64; o <<= 1) {
        int t = __shfl(incl, (lane - o) & 63);
        if (lane >= o) incl += t;
    }
    if (lane == 63) wsum[wid] = incl;
    __syncthreads();
    int wpref = 0;
    for (int w = 0; w < wid; ++w) wpref += wsum[w];
    if (b0 < NBUK) {
        int run = wpref + incl - s0;
        for (int k = 0; k < 4 && b0 + k < NBUK; ++k) {
            loc[b0 + k] = run;
            run += h[b0 + k];
        }
    }
    __syncthreads();
    for (int i = tid; i < NBUK; i += 256) {
        int c = h[i];
        cur[i] = c ? (atomicAdd(&bcur[i], c) + i * BUKCAP - loc[i]) : 0;
    }
    __syncthreads();
#pragma unroll
    for (int it = 0; it < SCT_TILE / 256; ++it) {
        if (dreg[it] >= 0) {
            int s = sreg[it], d = dreg[it];
            int b = d >> 7;
            unsigned pk = ((unsigned)(d & 127) << 17) | (unsigned)s;
            int pos = atomicAdd(&loc[b], 1);
            sp[pos] = pk;
            ga[pos] = (unsigned)(cur[b] + pos);
        }
    }
    __syncthreads();
    for (int i = tid; i < tilecnt; i += 256)
        pairs[ga[i]] = sp[i];
}

__global__ __launch_bounds__(256) void k_bsort(const int* __restrict__ bcur,
                                               unsigned* __restrict__ pairs,
                                               int* __restrict__ rowptr,
                                               int* __restrict__ cntd) {
    __shared__ unsigned sp[SH_CAP];
    __shared__ int hist[128], sc[128], cur2[128];
    int b = blockIdx.x;
    int cnt = bcur[b];
    if (cnt > SH_CAP) cnt = SH_CAP;
    int base = b * BUKCAP;
    int tid = threadIdx.x;
    if (tid < 128) hist[tid] = 0;
    __syncthreads();
    for (int i = tid; i < cnt; i += 256) {
        unsigned p = pairs[base + i];
        sp[i] = p;
        atomicAdd(&hist[p >> 17], 1);
    }
    __syncthreads();
    if (tid < 64) {
        int v0 = hist[2 * tid], v1 = hist[2 * tid + 1];
        int s = v0 + v1;
#pragma unroll
        for (int o = 1; o < 64; o <<= 1) {
            int t = __shfl(s, (tid - o) & 63);
            if (tid >= o) s += t;
        }
        int excl = s - v0 - v1;
        sc[2 * tid] = excl;
        sc[2 * tid + 1] = excl + v0;
    }
    __syncthreads();
    int nbase = b << 7;
    if (tid < 128 && nbase + tid < NN) {
        rowptr[nbase + tid] = base + sc[tid];
        cntd[nbase + tid]   = hist[tid];
        cur2[tid] = sc[tid];
    }
    __syncthreads();
    int* adj = (int*)pairs;
    for (int i = tid; i < cnt; i += 256) {
        unsigned p = sp[i];
        int ld = p >> 17;
        int pos = atomicAdd(&cur2[ld], 1);
        adj[base + pos] = (int)(p & 0x1FFFF);
    }
}

// ---------------- layer 1 generic fallback (deg>32): 64 lanes, chunked ----------------
__device__ __forceinline__ void agg1_node_gen(int n, int lane,
                                              const int* __restrict__ rowptr,
                                              const int* __restrict__ cntd,
                                              const int* __restrict__ adj,
                                              const float* __restrict__ ss1,
                                              const float* __restrict__ sd1,
                                              const float* __restrict__ xp,
                                              const float* __restrict__ W1,
                                              const float* __restrict__ b1,
                                              const float* __restrict__ W2,
                                              float* __restrict__ h2) {
    int off = rowptr[n], deg = cntd[n];
    float sdn = sd1[n];
    float m = -1e30f;
    for (int j0 = 0; j0 < deg; j0 += 64) {
        int j = j0 + lane;
        if (j < deg) {
            int s = adj[off + j];
            float e = ss1[s] + sdn;
            e = e > 0.f ? e : NEG * e;
            m = fmaxf(m, e);
        }
    }
#pragma unroll
    for (int o = 32; o; o >>= 1) m = fmaxf(m, __shfl_xor(m, o));
    float dsum = 0.f;
    for (int j0 = 0; j0 < deg; j0 += 64) {
        int j = j0 + lane;
        if (j < deg) {
            int s = adj[off + j];
            float e = ss1[s] + sdn;
            e = e > 0.f ? e : NEG * e;
            dsum += __expf(e - m);
        }
    }
#pragma unroll
    for (int o = 32; o; o >>= 1) dsum += __shfl_xor(dsum, o);
    float inv = 1.0f / dsum;
    float a0 = 0.f, a1 = 0.f, a2 = 0.f, a3 = 0.f, a4 = 0.f;
    for (int j0 = 0; j0 < deg; j0 += 64) {
        int j = j0 + lane;
        if (j < deg) {
            int s = adj[off + j];
            float e = ss1[s] + sdn;
            e = e > 0.f ? e : NEG * e;
            float w = __expf(e - m) * inv;
            const float4 xa = *(const float4*)(xp + (size_t)s * 8);
            float x4 = xp[(size_t)s * 8 + 4];
            a0 += w * xa.x; a1 += w * xa.y; a2 += w * xa.z; a3 += w * xa.w; a4 += w * x4;
        }
    }
#pragma unroll
    for (int o = 32; o; o >>= 1) {
        a0 += __shfl_xor(a0, o); a1 += __shfl_xor(a1, o); a2 += __shfl_xor(a2, o);
        a3 += __shfl_xor(a3, o); a4 += __shfl_xor(a4, o);
    }
    // epilogue: feature f = lane
    float of = b1[lane] + a0 * W1[lane] + a1 * W1[64 + lane] + a2 * W1[128 + lane]
             + a3 * W1[192 + lane] + a4 * W1[256 + lane];
    of = fmaxf(of, 0.f);
    float p2 = of * W2[lane];
#pragma unroll
    for (int o = 32; o; o >>= 1) p2 += __shfl_xor(p2, o);
    if (lane == 0) h2[n] = p2;
}

// ---------------- layer 1: lane=edge, 2 nodes per wave ----------------
__global__ __launch_bounds__(256) void k_agg1(const int* __restrict__ rowptr,
                                              const int* __restrict__ cntd,
                                              const int* __restrict__ adj,
                                              const float* __restrict__ ss1,
                                              const float* __restrict__ sd1,
                                              const float* __restrict__ xp,
                                              const float* __restrict__ W1,
                                              const float* __restrict__ b1,
                                              const float* __restrict__ W2,
                                              float* __restrict__ h2) {
    int wid  = threadIdx.x >> 6;
    int lane = threadIdx.x & 63;
    int n0 = (blockIdx.x * 4 + wid) * 2;
    if (n0 >= NN) return;
    int d0 = cntd[n0], d1 = cntd[n0 + 1];

    if (d0 <= 32 && d1 <= 32) {
        int half = lane >> 5, li = lane & 31;
        int n = n0 + half;
        int off = rowptr[n];
        int deg = half ? d1 : d0;
        float sdn = sd1[n];
        int s = adj[off + (li < deg ? li : 0)];
        // issue the x-row loads early (independent of softmax chain)
        const float4 xa = *(const float4*)(xp + (size_t)s * 8);
        float x4 = xp[(size_t)s * 8 + 4];
        float t = ss1[s] + sdn;
        float e = t > 0.f ? t : NEG * t;
        if (li >= deg) e = -1e30f;
        float m = e;
#pragma unroll
        for (int o = 1; o <= 16; o <<= 1) m = fmaxf(m, __shfl_xor(m, o));
        float p = (li < deg) ? __expf(e - m) : 0.f;
        float ds = p;
#pragma unroll
        for (int o = 1; o <= 16; o <<= 1) ds += __shfl_xor(ds, o);
        float w = p * (1.0f / ds);
        float a0 = w * xa.x, a1 = w * xa.y, a2 = w * xa.z, a3 = w * xa.w, a4 = w * x4;
#pragma unroll
        for (int o = 1; o <= 16; o <<= 1) {
            a0 += __shfl_xor(a0, o); a1 += __shfl_xor(a1, o); a2 += __shfl_xor(a2, o);
            a3 += __shfl_xor(a3, o); a4 += __shfl_xor(a4, o);
        }
        // epilogue: lane li covers features li and li+32
        float o0 = b1[li] + a0 * W1[li] + a1 * W1[64 + li] + a2 * W1[128 + li]
                 + a3 * W1[192 + li] + a4 * W1[256 + li];
        float o1 = b1[li + 32] + a0 * W1[li + 32] + a1 * W1[96 + li] + a2 * W1[160 + li]
                 + a3 * W1[224 + li] + a4 * W1[288 + li];
        o0 = fmaxf(o0, 0.f);
        o1 = fmaxf(o1, 0.f);
        float p2 = o0 * W2[li] + o1 * W2[li + 32];
#pragma unroll
        for (int o = 1; o <= 16; o <<= 1) p2 += __shfl_xor(p2, o);
        if (li == 0) h2[n] = p2;
    } else {
        agg1_node_gen(n0,     lane, rowptr, cntd, adj, ss1, sd1, xp, W1, b1, W2, h2);
        agg1_node_gen(n0 + 1, lane, rowptr, cntd, adj, ss1, sd1, xp, W1, b1, W2, h2);
    }
}

// ---------------- layer 2: full-wave single-node fallback ----------------
__device__ __forceinline__ void agg2_node(int n, int lane,
                                          const int* __restrict__ rowptr,
                                          const int* __restrict__ cntd,
                                          const int* __restrict__ adj,
                                          const float* __restrict__ h2,
                                          float as2v, float ad2v, float b2v,
                                          float* __restrict__ out) {
    int off = rowptr[n], deg = cntd[n];
    float sdn = h2[n] * ad2v;
    float m = -1e30f;
    for (int j0 = 0; j0 < deg; j0 += 64) {
        int j = j0 + lane;
        if (j < deg) {
            int s = adj[off + j];
            float e = h2[s] * as2v + sdn;
            e = e > 0.f ? e : NEG * e;
            m = fmaxf(m, e);
        }
    }
#pragma unroll
    for (int o = 32; o; o >>= 1) m = fmaxf(m, __shfl_xor(m, o));
    float dsum = 0.f, nsum = 0.f;
    for (int j0 = 0; j0 < deg; j0 += 64) {
        int j = j0 + lane;
        if (j < deg) {
            int s = adj[off + j];
            float hv = h2[s];
            float e = hv * as2v + sdn;
            e = e > 0.f ? e : NEG * e;
            float ex = __expf(e - m);
            dsum += ex;
            nsum += ex * hv;
        }
    }
#pragma unroll
    for (int o = 32; o; o >>= 1) { dsum += __shfl_xor(dsum, o); nsum += __shfl_xor(nsum, o); }
    if (lane == 0) out[n] = nsum / dsum + b2v;
}

// ---------------- layer 2: 4 nodes per wave ----------------
__global__ __launch_bounds__(256) void k_agg2(const int* __restrict__ rowptr,
                                              const int* __restrict__ cntd,
                                              const int* __restrict__ adj,
                                              const float* __restrict__ h2,
                                              const float* __restrict__ as2,
                                              const float* __restrict__ ad2,
                                              const float* __restrict__ b2,
                                              float* __restrict__ out) {
    int wid  = threadIdx.x >> 6;
    int lane = threadIdx.x & 63;
    int n0 = (blockIdx.x * 4 + wid) * 4;
    if (n0 >= NN) return;
    float as2v = as2[0], ad2v = ad2[0], b2v = b2[0];
    int d0 = cntd[n0], d1 = cntd[n0 + 1], d2 = cntd[n0 + 2], d3 = cntd[n0 + 3];

    if (d0 <= 32 && d1 <= 32 && d2 <= 32 && d3 <= 32) {
        int half = lane >> 5, li = lane & 31;
        int nA = n0 + half, nB = n0 + 2 + half;
        int offA = rowptr[nA], offB = rowptr[nB];
        int degA = half ? d1 : d0, degB = half ? d3 : d2;
        float sdA = h2[nA] * ad2v, sdB = h2[nB] * ad2v;
        float hvA = 0.f, hvB = 0.f, eA = -1e30f, eB = -1e30f;
        if (li < degA) {
            hvA = h2[adj[offA + li]];
            float t = hvA * as2v + sdA;
            eA = t > 0.f ? t : NEG * t;
        }
        if (li < degB) {
            hvB = h2[adj[offB + li]];
            float t = hvB * as2v + sdB;
            eB = t > 0.f ? t : NEG * t;
        }
        float mA = eA, mB = eB;
#pragma unroll
        for (int o = 1; o <= 16; o <<= 1) {
            mA = fmaxf(mA, __shfl_xor(mA, o));
            mB = fmaxf(mB, __shfl_xor(mB, o));
        }
        float pA = (li < degA) ? __expf(eA - mA) : 0.f;
        float pB = (li < degB) ? __expf(eB - mB) : 0.f;
        float dsA = pA, dsB = pB, nsA = pA * hvA, nsB = pB * hvB;
#pragma unroll
        for (int o = 1; o <= 16; o <<= 1) {
            dsA += __shfl_xor(dsA, o); nsA += __shfl_xor(nsA, o);
            dsB += __shfl_xor(dsB, o); nsB += __shfl_xor(nsB, o);
        }
        if (li == 0) {
            out[nA] = nsA / dsA + b2v;
            out[nB] = nsB / dsB + b2v;
        }
    } else {
        agg2_node(n0,     lane, rowptr, cntd, adj, h2, as2v, ad2v, b2v, out);
        agg2_node(n0 + 1, lane, rowptr, cntd, adj, h2, as2v, ad2v, b2v, out);
        agg2_node(n0 + 2, lane, rowptr, cntd, adj, h2, as2v, ad2v, b2v, out);
        agg2_node(n0 + 3, lane, rowptr, cntd, adj, h2, as2v, ad2v, b2v, out);
    }
}

extern "C" void kernel_launch(void* const* d_in, const int* in_sizes, int n_in,
                              void* d_out, int out_size, void* d_ws, size_t ws_size,
                              hipStream_t stream) {
    const float* x      = (const float*)d_in[0];
    const int*   ei     = (const int*)d_in[1];
    const float* W1     = (const float*)d_in[2];
    const float* a_src1 = (const float*)d_in[3];
    const float* a_dst1 = (const float*)d_in[4];
    const float* b1     = (const float*)d_in[5];
    const float* W2     = (const float*)d_in[6];
    const float* as2    = (const float*)d_in[7];
    const float* ad2    = (const float*)d_in[8];
    const float* b2     = (const float*)d_in[9];
    float* out = (float*)d_out;

    // workspace layout (all 4-byte elements)
    float* xp   = (float*)d_ws;                         // N*8 f32 = 3.2MB
    float* ss1  = xp + (size_t)NN * 8;                  // N
    float* sd1  = ss1 + NN;                             // N
    float* h2   = sd1 + NN;                             // N
    int* rowptr = (int*)(h2 + NN);                      // N
    int* cntd   = rowptr + NN;                          // N
    int* bcur   = cntd + NN;                            // 1024
    unsigned* pairs = (unsigned*)(bcur + 1024);         // NBUK*BUKCAP (reused as adj)
    int* adj    = (int*)pairs;

    const int NSCT = (ET + SCT_TILE - 1) / SCT_TILE;    // 416
    const int NPAIR = (NN / 2 + 3) / 4;                 // 12500 blocks, 2 nodes/wave
    const int NQUAD = (NN + 15) / 16;                   // 6250 blocks, 4 nodes/wave

    k_proj<<<(NN + 3) / 4, 256, 0, stream>>>(x, W1, a_src1, a_dst1, xp, ss1, sd1, bcur);
    k_bscatter<<<NSCT, 256, 0, stream>>>(ei, bcur, pairs);
    k_bsort<<<NBUK, 256, 0, stream>>>(bcur, pairs, rowptr, cntd);
    k_agg1<<<NPAIR, 256, 0, stream>>>(rowptr, cntd, adj, ss1, sd1, xp, W1, b1, W2, h2);
    k_agg2<<<NQUAD, 256, 0, stream>>>(rowptr, cntd, adj, h2, as2, ad2, b2, out);
}